// Round 3
// baseline (412.604 us; speedup 1.0000x reference)
//
#include <hip/hip_runtime.h>
#include <hip/hip_bf16.h>

#define N_GROUPS 368
#define NMODELS  64
#define BATCH    4096
#define ROWS_PER_BLOCK 256

__global__ __launch_bounds__(ROWS_PER_BLOCK) void ensemble_kernel(
    const float* __restrict__ x,     // [BATCH][N_GROUPS][NMODELS]
    const float* __restrict__ W,     // [N_GROUPS][NMODELS][NMODELS]
    const float* __restrict__ bias,  // [N_GROUPS][NMODELS]
    float* __restrict__ out)         // [BATCH][N_GROUPS]
{
    const int g   = blockIdx.y;                          // group (wave-uniform)
    const int row = blockIdx.x * ROWS_PER_BLOCK + threadIdx.x;

    const float* __restrict__ xr = x + ((size_t)row * N_GROUPS + g) * NMODELS;
    const float* __restrict__ Wg = W + (size_t)g * NMODELS * NMODELS;  // uniform -> s_load
    const float* __restrict__ bg = bias + (size_t)g * NMODELS;         // uniform -> s_load

    // x row -> 64 VGPRs via 16 float4 loads (256B per thread, every byte used)
    float xv[NMODELS];
    #pragma unroll
    for (int i = 0; i < NMODELS / 4; ++i) {
        const float4 v = reinterpret_cast<const float4*>(xr)[i];
        xv[4*i+0] = v.x; xv[4*i+1] = v.y; xv[4*i+2] = v.z; xv[4*i+3] = v.w;
    }

    // y = W[g] @ x + b[g] : 64 independent 64-FMA chains, W from SGPRs
    float y[NMODELS];
    #pragma unroll
    for (int m = 0; m < NMODELS; ++m) {
        float acc = bg[m];
        #pragma unroll
        for (int n = 0; n < NMODELS; ++n)
            acc = __builtin_fmaf(xv[n], Wg[m * NMODELS + n], acc);
        y[m] = acc;
    }

    // softmax over m, fused with weighted reduction against x
    float mx = y[0];
    #pragma unroll
    for (int m = 1; m < NMODELS; ++m) mx = fmaxf(mx, y[m]);

    float s = 0.0f, p = 0.0f;
    #pragma unroll
    for (int m = 0; m < NMODELS; ++m) {
        const float e = __expf(y[m] - mx);
        s += e;
        p = __builtin_fmaf(e, xv[m], p);
    }

    out[(size_t)row * N_GROUPS + g] = p / s;
}

extern "C" void kernel_launch(void* const* d_in, const int* in_sizes, int n_in,
                              void* d_out, int out_size, void* d_ws, size_t ws_size,
                              hipStream_t stream) {
    const float* x  = (const float*)d_in[0];
    const float* W  = (const float*)d_in[1];
    const float* b  = (const float*)d_in[2];
    float* out = (float*)d_out;

    dim3 grid(BATCH / ROWS_PER_BLOCK, N_GROUPS);
    dim3 block(ROWS_PER_BLOCK);
    ensemble_kernel<<<grid, block, 0, stream>>>(x, W, b, out);
}

// Round 4
// 138.332 us; speedup vs baseline: 2.9827x; 2.9827x over previous
//
#include <hip/hip_runtime.h>
#include <hip/hip_bf16.h>

#define N_GROUPS 368
#define NMODELS  64
#define BATCH    4096
#define ROWS     128   // batch rows per block

typedef __attribute__((ext_vector_type(8))) short short8v;  // 8 bf16 (4 VGPRs)
typedef __attribute__((ext_vector_type(4))) float f32x4;    // MFMA accumulator

// split fp32 into bf16 hi + bf16 lo (residual); x ≈ hi + lo to ~2^-16 rel
__device__ inline void bf_split(float v, unsigned short& hi, unsigned short& lo) {
    const __hip_bfloat16 h = __float2bfloat16(v);
    const float r = v - __bfloat162float(h);
    const __hip_bfloat16 l = __float2bfloat16(r);
    hi = __builtin_bit_cast(unsigned short, h);
    lo = __builtin_bit_cast(unsigned short, l);
}

// XOR swizzle (16B granule) on the row-relative SHORT offset: flips short-bit3
// (= byte-bit4). Write and read use the same involution -> consistent.
#define SWZ(row, soff) ((soff) ^ (((row) & 7) << 3))

__global__ __launch_bounds__(256, 3) void ensemble_mfma(
    const float* __restrict__ x,     // [BATCH][N_GROUPS][NMODELS]
    const float* __restrict__ W,     // [N_GROUPS][NMODELS][NMODELS]
    const float* __restrict__ bias,  // [N_GROUPS][NMODELS]
    float* __restrict__ out)         // [BATCH][N_GROUPS]
{
    __shared__ __hip_bfloat16 Xh[ROWS * 64];  // 16 KB  [row][n] swizzled
    __shared__ __hip_bfloat16 Xl[ROWS * 64];  // 16 KB
    __shared__ __hip_bfloat16 Wh[64 * 64];    //  8 KB  [m][n] swizzled
    __shared__ __hip_bfloat16 Wl[64 * 64];    //  8 KB  -> 48 KB total, 3 blocks/CU

    const int g    = blockIdx.y;
    const int row0 = blockIdx.x * ROWS;
    const int t    = threadIdx.x;
    const int q    = t >> 4;      // 0..15 row group
    const int ui   = t & 15;      // 16 lanes cover one 256B row (4 lines vs 16 naive)

    // ---- stage X: 128 rows x 64 fp32 -> bf16 hi/lo in LDS ----
    #pragma unroll
    for (int j = 0; j < 8; ++j) {
        const int r = q + 16 * j;
        const float4 v = *reinterpret_cast<const float4*>(
            x + ((size_t)(row0 + r) * N_GROUPS + g) * NMODELS + 4 * ui);
        unsigned short h0,h1,h2,h3, l0,l1,l2,l3;
        bf_split(v.x, h0, l0); bf_split(v.y, h1, l1);
        bf_split(v.z, h2, l2); bf_split(v.w, h3, l3);
        const int so = r * 64 + SWZ(r, 4 * ui);
        *reinterpret_cast<short4*>(&Xh[so]) = make_short4((short)h0,(short)h1,(short)h2,(short)h3);
        *reinterpret_cast<short4*>(&Xl[so]) = make_short4((short)l0,(short)l1,(short)l2,(short)l3);
    }
    // ---- stage W[g]: 64x64 fp32 -> bf16 hi/lo ----
    #pragma unroll
    for (int j = 0; j < 4; ++j) {
        const int m = q + 16 * j;
        const float4 v = *reinterpret_cast<const float4*>(
            W + ((size_t)g * 64 + m) * 64 + 4 * ui);
        unsigned short h0,h1,h2,h3, l0,l1,l2,l3;
        bf_split(v.x, h0, l0); bf_split(v.y, h1, l1);
        bf_split(v.z, h2, l2); bf_split(v.w, h3, l3);
        const int so = m * 64 + SWZ(m, 4 * ui);
        *reinterpret_cast<short4*>(&Wh[so]) = make_short4((short)h0,(short)h1,(short)h2,(short)h3);
        *reinterpret_cast<short4*>(&Wl[so]) = make_short4((short)l0,(short)l1,(short)l2,(short)l3);
    }
    __syncthreads();

    const int lane = t & 63;
    const int wv   = t >> 6;      // wave id: rows [wv*32, wv*32+32)
    const int u    = lane & 15;   // frag row/col within 16
    const int h    = lane >> 4;   // k-chunk selector (8 bf16 each)

    // bias -> accumulator init (col m = cf*16+u, same for all 4 regs)
    float bv[4];
    #pragma unroll
    for (int cf = 0; cf < 4; ++cf) bv[cf] = bias[(size_t)g * 64 + cf * 16 + u];

    f32x4 acc[2][4];
    #pragma unroll
    for (int rf = 0; rf < 2; ++rf)
        #pragma unroll
        for (int cf = 0; cf < 4; ++cf) {
            acc[rf][cf][0] = bv[cf]; acc[rf][cf][1] = bv[cf];
            acc[rf][cf][2] = bv[cf]; acc[rf][cf][3] = bv[cf];
        }

    // ---- MFMA: Y = X·W^T via 3-product bf16 split, K=64 in 2 steps ----
    #pragma unroll
    for (int ks = 0; ks < 2; ++ks) {
        short8v ah[2], al[2], bh[4], bl[4];
        #pragma unroll
        for (int rf = 0; rf < 2; ++rf) {
            const int row = wv * 32 + rf * 16 + u;
            const int so  = row * 64 + SWZ(row, ks * 32 + h * 8);
            ah[rf] = *reinterpret_cast<const short8v*>(&Xh[so]);
            al[rf] = *reinterpret_cast<const short8v*>(&Xl[so]);
        }
        #pragma unroll
        for (int cf = 0; cf < 4; ++cf) {
            const int m  = cf * 16 + u;
            const int so = m * 64 + SWZ(m, ks * 32 + h * 8);
            bh[cf] = *reinterpret_cast<const short8v*>(&Wh[so]);
            bl[cf] = *reinterpret_cast<const short8v*>(&Wl[so]);
        }
        #pragma unroll
        for (int rf = 0; rf < 2; ++rf)
            #pragma unroll
            for (int cf = 0; cf < 4; ++cf) {
                acc[rf][cf] = __builtin_amdgcn_mfma_f32_16x16x32_bf16(ah[rf], bh[cf], acc[rf][cf], 0, 0, 0);
                acc[rf][cf] = __builtin_amdgcn_mfma_f32_16x16x32_bf16(ah[rf], bl[cf], acc[rf][cf], 0, 0, 0);
                acc[rf][cf] = __builtin_amdgcn_mfma_f32_16x16x32_bf16(al[rf], bh[cf], acc[rf][cf], 0, 0, 0);
            }
    }

    // ---- epilogue: softmax over cols + dot with x, all in-register ----
    // D layout (m89/m91): row = 4*h + reg, col = cf*16 + u  (within 16x16 frag)
    // row (rf,h,p)'s 64 y-values live in the 16 lanes of group h -> shfl_xor<16>
    #pragma unroll
    for (int rf = 0; rf < 2; ++rf)
        #pragma unroll
        for (int p = 0; p < 4; ++p) {
            const int rloc = wv * 32 + rf * 16 + 4 * h + p;
            float mx = fmaxf(fmaxf(acc[rf][0][p], acc[rf][1][p]),
                             fmaxf(acc[rf][2][p], acc[rf][3][p]));
            #pragma unroll
            for (int s_ = 1; s_ < 16; s_ <<= 1) mx = fmaxf(mx, __shfl_xor(mx, s_));
            float S = 0.f, P = 0.f;
            #pragma unroll
            for (int cf = 0; cf < 4; ++cf) {
                const float e = __expf(acc[rf][cf][p] - mx);
                S += e;
                const int mcol = cf * 16 + u;
                const int so   = rloc * 64 + SWZ(rloc, mcol);
                const float xv = __bfloat162float(Xh[so]) + __bfloat162float(Xl[so]);
                P = __builtin_fmaf(e, xv, P);
            }
            #pragma unroll
            for (int s_ = 1; s_ < 16; s_ <<= 1) {
                S += __shfl_xor(S, s_);
                P += __shfl_xor(P, s_);
            }
            if (u == rf * 4 + p)
                out[(size_t)(row0 + rloc) * N_GROUPS + g] = P / S;
        }
}

extern "C" void kernel_launch(void* const* d_in, const int* in_sizes, int n_in,
                              void* d_out, int out_size, void* d_ws, size_t ws_size,
                              hipStream_t stream) {
    const float* x  = (const float*)d_in[0];
    const float* W  = (const float*)d_in[1];
    const float* b  = (const float*)d_in[2];
    float* out = (float*)d_out;

    dim3 grid(BATCH / ROWS, N_GROUPS);
    dim3 block(256);
    ensemble_mfma<<<grid, block, 0, stream>>>(x, W, b, out);
}

// Round 7
// 109.441 us; speedup vs baseline: 3.7701x; 1.2640x over previous
//
#include <hip/hip_runtime.h>
#include <hip/hip_bf16.h>

#define N_GROUPS 368
#define NMODELS  64
#define BATCH    4096
#define ROWS     128   // batch rows per block (4 waves x 32)

typedef __attribute__((ext_vector_type(8)))  short short8v;  // 8 bf16 (4 VGPRs)
typedef __attribute__((ext_vector_type(16))) float f32x16;   // 32x32 MFMA acc

// split fp32 into bf16 hi + bf16 lo (residual)
__device__ inline void bf_split(float v, unsigned short& hi, unsigned short& lo) {
    const __hip_bfloat16 h = __float2bfloat16(v);
    const float r = v - __bfloat162float(h);
    const __hip_bfloat16 l = __float2bfloat16(r);
    hi = __builtin_bit_cast(unsigned short, h);
    lo = __builtin_bit_cast(unsigned short, l);
}

__device__ inline float bf2f(short u) {
    return __builtin_bit_cast(float, ((unsigned)(unsigned short)u) << 16);
}

// XOR swizzle on row-relative SHORT offset: flips short-bits 3..5 (16B..64B).
// Same involution on write and read -> memory[q] = logical[q ^ s(row)].
#define SWZ(row, soff) ((soff) ^ (((row) & 7) << 3))

__global__ __launch_bounds__(256, 3) void ensemble_mfma_t(
    const float* __restrict__ x,     // [BATCH][N_GROUPS][NMODELS]
    const float* __restrict__ W,     // [N_GROUPS][NMODELS][NMODELS]
    const float* __restrict__ bias,  // [N_GROUPS][NMODELS]
    float* __restrict__ out)         // [BATCH][N_GROUPS]
{
    __shared__ __hip_bfloat16 Xh[ROWS * 64];  // 16 KB
    __shared__ __hip_bfloat16 Xl[ROWS * 64];  // 16 KB
    __shared__ __hip_bfloat16 Wh[64 * 64];    //  8 KB
    __shared__ __hip_bfloat16 Wl[64 * 64];    //  8 KB  -> 48 KB, 3 blocks/CU

    const int g    = blockIdx.y;
    const int row0 = blockIdx.x * ROWS;
    const int t    = threadIdx.x;
    const int q    = t >> 4;      // 0..15
    const int ui   = t & 15;      // 16 lanes cover one 256B fp32 row

    // ---- stage X: 128 rows x 64 fp32 -> bf16 hi/lo (swizzled) ----
    #pragma unroll
    for (int j = 0; j < 8; ++j) {
        const int r = q + 16 * j;
        const float4 v = *reinterpret_cast<const float4*>(
            x + ((size_t)(row0 + r) * N_GROUPS + g) * NMODELS + 4 * ui);
        unsigned short h0,h1,h2_,h3, l0,l1,l2,l3;
        bf_split(v.x, h0, l0); bf_split(v.y, h1, l1);
        bf_split(v.z, h2_, l2); bf_split(v.w, h3, l3);
        const int so = r * 64 + SWZ(r, 4 * ui);
        *reinterpret_cast<short4*>(&Xh[so]) = make_short4((short)h0,(short)h1,(short)h2_,(short)h3);
        *reinterpret_cast<short4*>(&Xl[so]) = make_short4((short)l0,(short)l1,(short)l2,(short)l3);
    }
    // ---- stage W[g]: 64x64 fp32 -> bf16 hi/lo (swizzled) ----
    #pragma unroll
    for (int j = 0; j < 4; ++j) {
        const int m = q + 16 * j;
        const float4 v = *reinterpret_cast<const float4*>(
            W + ((size_t)g * 64 + m) * 64 + 4 * ui);
        unsigned short h0,h1,h2_,h3, l0,l1,l2,l3;
        bf_split(v.x, h0, l0); bf_split(v.y, h1, l1);
        bf_split(v.z, h2_, l2); bf_split(v.w, h3, l3);
        const int so = m * 64 + SWZ(m, 4 * ui);
        *reinterpret_cast<short4*>(&Wh[so]) = make_short4((short)h0,(short)h1,(short)h2_,(short)h3);
        *reinterpret_cast<short4*>(&Wl[so]) = make_short4((short)l0,(short)l1,(short)l2,(short)l3);
    }

    const int lane = t & 63;
    const int wv   = t >> 6;      // wave id -> batch-col tile [wv*32, wv*32+32)
    const int cl   = lane & 31;   // frag row index (W-row m or X-row c)
    const int h2   = lane >> 5;   // k-group selector

    // bias for this lane's 32 m-slots (only h2 varies per lane; L2/L3-hot)
    float bv[2][16];
    #pragma unroll
    for (int tt = 0; tt < 2; ++tt)
        #pragma unroll
        for (int r = 0; r < 16; ++r)
            bv[tt][r] = bias[(size_t)g * 64 + tt * 32 + (r & 3) + 8 * (r >> 2) + 4 * h2];

    __syncthreads();

    // ---- MFMA: Y^T = W . X^T ; D col = batch row (lane&31), D row = m ----
    f32x16 acc0, acc1;
    #pragma unroll
    for (int r = 0; r < 16; ++r) { acc0[r] = 0.f; acc1[r] = 0.f; }

    const int c = wv * 32 + cl;   // this lane's batch row (B-operand row)
    #pragma unroll
    for (int ks = 0; ks < 4; ++ks) {
        const int ko = ks * 16 + 8 * h2;
        const int xo = c * 64 + SWZ(c, ko);
        const short8v bh = *reinterpret_cast<const short8v*>(&Xh[xo]);
        const short8v bl = *reinterpret_cast<const short8v*>(&Xl[xo]);

        const int wo0 = cl * 64 + SWZ(cl, ko);          // m = cl (tile 0)
        const short8v ah0 = *reinterpret_cast<const short8v*>(&Wh[wo0]);
        const short8v al0 = *reinterpret_cast<const short8v*>(&Wl[wo0]);
        acc0 = __builtin_amdgcn_mfma_f32_32x32x16_bf16(ah0, bh, acc0, 0, 0, 0);
        acc0 = __builtin_amdgcn_mfma_f32_32x32x16_bf16(ah0, bl, acc0, 0, 0, 0);
        acc0 = __builtin_amdgcn_mfma_f32_32x32x16_bf16(al0, bh, acc0, 0, 0, 0);

        const int m1  = 32 + cl;                        // tile 1
        const int wo1 = m1 * 64 + SWZ(m1, ko);
        const short8v ah1 = *reinterpret_cast<const short8v*>(&Wh[wo1]);
        const short8v al1 = *reinterpret_cast<const short8v*>(&Wl[wo1]);
        acc1 = __builtin_amdgcn_mfma_f32_32x32x16_bf16(ah1, bh, acc1, 0, 0, 0);
        acc1 = __builtin_amdgcn_mfma_f32_32x32x16_bf16(ah1, bl, acc1, 0, 0, 0);
        acc1 = __builtin_amdgcn_mfma_f32_32x32x16_bf16(al1, bh, acc1, 0, 0, 0);
    }

    // ---- epilogue: softmax over m (in-register) + dot with x ----
    // lane holds m = tt*32 + (r&3) + 8*(r>>2) + 4*h2 ; other half via 1 shfl
    float y[2][16];
    #pragma unroll
    for (int r = 0; r < 16; ++r) { y[0][r] = acc0[r] + bv[0][r]; y[1][r] = acc1[r] + bv[1][r]; }

    float mx = y[0][0];
    #pragma unroll
    for (int r = 1; r < 16; ++r) mx = fmaxf(mx, y[0][r]);
    #pragma unroll
    for (int r = 0; r < 16; ++r) mx = fmaxf(mx, y[1][r]);
    mx = fmaxf(mx, __shfl_xor(mx, 32));

    float S = 0.f, P = 0.f;
    #pragma unroll
    for (int tt = 0; tt < 2; ++tt)
        #pragma unroll
        for (int j = 0; j < 4; ++j) {
            // x[c][m] for m-group tt*32 + 8j + 4*h2 .. +3  (4 consecutive m)
            const int so = c * 64 + SWZ(c, tt * 32 + 8 * j + 4 * h2);
            const short4 vh = *reinterpret_cast<const short4*>(&Xh[so]);
            const short4 vl = *reinterpret_cast<const short4*>(&Xl[so]);
            const float xv0 = bf2f(vh.x) + bf2f(vl.x);
            const float xv1 = bf2f(vh.y) + bf2f(vl.y);
            const float xv2 = bf2f(vh.z) + bf2f(vl.z);
            const float xv3 = bf2f(vh.w) + bf2f(vl.w);
            const float e0 = __expf(y[tt][4*j+0] - mx);
            const float e1 = __expf(y[tt][4*j+1] - mx);
            const float e2 = __expf(y[tt][4*j+2] - mx);
            const float e3 = __expf(y[tt][4*j+3] - mx);
            S += (e0 + e1) + (e2 + e3);
            P = __builtin_fmaf(e0, xv0, P);
            P = __builtin_fmaf(e1, xv1, P);
            P = __builtin_fmaf(e2, xv2, P);
            P = __builtin_fmaf(e3, xv3, P);
        }
    S += __shfl_xor(S, 32);
    P += __shfl_xor(P, 32);

    if (h2 == 0)
        out[(size_t)(row0 + c) * N_GROUPS + g] = P / S;
}

extern "C" void kernel_launch(void* const* d_in, const int* in_sizes, int n_in,
                              void* d_out, int out_size, void* d_ws, size_t ws_size,
                              hipStream_t stream) {
    const float* x  = (const float*)d_in[0];
    const float* W  = (const float*)d_in[1];
    const float* b  = (const float*)d_in[2];
    float* out = (float*)d_out;

    dim3 grid(BATCH / ROWS, N_GROUPS);
    dim3 block(256);
    ensemble_mfma_t<<<grid, block, 0, stream>>>(x, W, b, out);
}

// Round 8
// 108.685 us; speedup vs baseline: 3.7963x; 1.0070x over previous
//
#include <hip/hip_runtime.h>
#include <hip/hip_bf16.h>

#define N_GROUPS 368
#define NMODELS  64
#define BATCH    4096
#define ROWS     256   // batch rows per block (8 waves x 32)

typedef __attribute__((ext_vector_type(8)))  short short8v;  // 8 bf16 (4 VGPRs)
typedef __attribute__((ext_vector_type(16))) float f32x16;   // 32x32 MFMA acc

// split fp32 into bf16 hi + bf16 lo (residual)
__device__ inline void bf_split(float v, unsigned short& hi, unsigned short& lo) {
    const __hip_bfloat16 h = __float2bfloat16(v);
    const float r = v - __bfloat162float(h);
    const __hip_bfloat16 l = __float2bfloat16(r);
    hi = __builtin_bit_cast(unsigned short, h);
    lo = __builtin_bit_cast(unsigned short, l);
}

__device__ inline float bf2f(short u) {
    return __builtin_bit_cast(float, ((unsigned)(unsigned short)u) << 16);
}

// XOR swizzle on row-relative SHORT offset: flips short-bits 3..5 (16B..64B).
// Same involution on write and read -> memory[q] = logical[q ^ s(row)].
#define SWZ(row, soff) ((soff) ^ (((row) & 7) << 3))

__global__ __launch_bounds__(512, 4) void ensemble_mfma_t(
    const float* __restrict__ x,     // [BATCH][N_GROUPS][NMODELS]
    const float* __restrict__ W,     // [N_GROUPS][NMODELS][NMODELS]
    const float* __restrict__ bias,  // [N_GROUPS][NMODELS]
    float* __restrict__ out)         // [BATCH][N_GROUPS]
{
    __shared__ __hip_bfloat16 Xh[ROWS * 64];  // 32 KB
    __shared__ __hip_bfloat16 Xl[ROWS * 64];  // 32 KB
    __shared__ __hip_bfloat16 Wh[64 * 64];    //  8 KB
    __shared__ __hip_bfloat16 Wl[64 * 64];    //  8 KB  -> 80 KB, 2 blocks/CU (16 waves)

    const int g    = blockIdx.y;
    const int row0 = blockIdx.x * ROWS;
    const int t    = threadIdx.x;
    const int q    = t >> 4;      // 0..31
    const int ui   = t & 15;      // 16 lanes cover one 256B fp32 row

    // ---- stage X: 256 rows x 64 fp32 -> bf16 hi/lo (swizzled) ----
    #pragma unroll
    for (int j = 0; j < 8; ++j) {
        const int r = q + 32 * j;
        const float4 v = *reinterpret_cast<const float4*>(
            x + ((size_t)(row0 + r) * N_GROUPS + g) * NMODELS + 4 * ui);
        unsigned short h0,h1,h2_,h3, l0,l1,l2,l3;
        bf_split(v.x, h0, l0); bf_split(v.y, h1, l1);
        bf_split(v.z, h2_, l2); bf_split(v.w, h3, l3);
        const int so = r * 64 + SWZ(r, 4 * ui);
        *reinterpret_cast<short4*>(&Xh[so]) = make_short4((short)h0,(short)h1,(short)h2_,(short)h3);
        *reinterpret_cast<short4*>(&Xl[so]) = make_short4((short)l0,(short)l1,(short)l2,(short)l3);
    }
    // ---- stage W[g]: 64x64 fp32 -> bf16 hi/lo (swizzled) ----
    #pragma unroll
    for (int j = 0; j < 2; ++j) {
        const int m = q + 32 * j;
        const float4 v = *reinterpret_cast<const float4*>(
            W + ((size_t)g * 64 + m) * 64 + 4 * ui);
        unsigned short h0,h1,h2_,h3, l0,l1,l2,l3;
        bf_split(v.x, h0, l0); bf_split(v.y, h1, l1);
        bf_split(v.z, h2_, l2); bf_split(v.w, h3, l3);
        const int so = m * 64 + SWZ(m, 4 * ui);
        *reinterpret_cast<short4*>(&Wh[so]) = make_short4((short)h0,(short)h1,(short)h2_,(short)h3);
        *reinterpret_cast<short4*>(&Wl[so]) = make_short4((short)l0,(short)l1,(short)l2,(short)l3);
    }

    const int lane = t & 63;
    const int wv   = t >> 6;      // wave id -> batch-row tile [wv*32, wv*32+32)
    const int cl   = lane & 31;   // frag row index (W-row m or X-row c)
    const int h2   = lane >> 5;   // k-group selector

    __syncthreads();

    // ---- MFMA: Y^T = W . X^T ; D col = batch row (lane&31), D row = m ----
    f32x16 acc0, acc1;
    #pragma unroll
    for (int r = 0; r < 16; ++r) { acc0[r] = 0.f; acc1[r] = 0.f; }

    const int c = wv * 32 + cl;   // this lane's batch row (B-operand row)
    #pragma unroll
    for (int ks = 0; ks < 4; ++ks) {
        const int ko = ks * 16 + 8 * h2;
        const int xo = c * 64 + SWZ(c, ko);
        const short8v bh = *reinterpret_cast<const short8v*>(&Xh[xo]);
        const short8v bl = *reinterpret_cast<const short8v*>(&Xl[xo]);

        const int wo0 = cl * 64 + SWZ(cl, ko);          // m = cl (tile 0)
        const short8v ah0 = *reinterpret_cast<const short8v*>(&Wh[wo0]);
        const short8v al0 = *reinterpret_cast<const short8v*>(&Wl[wo0]);
        acc0 = __builtin_amdgcn_mfma_f32_32x32x16_bf16(ah0, bh, acc0, 0, 0, 0);
        acc0 = __builtin_amdgcn_mfma_f32_32x32x16_bf16(ah0, bl, acc0, 0, 0, 0);
        acc0 = __builtin_amdgcn_mfma_f32_32x32x16_bf16(al0, bh, acc0, 0, 0, 0);

        const int m1  = 32 + cl;                        // tile 1
        const int wo1 = m1 * 64 + SWZ(m1, ko);
        const short8v ah1 = *reinterpret_cast<const short8v*>(&Wh[wo1]);
        const short8v al1 = *reinterpret_cast<const short8v*>(&Wl[wo1]);
        acc1 = __builtin_amdgcn_mfma_f32_32x32x16_bf16(ah1, bh, acc1, 0, 0, 0);
        acc1 = __builtin_amdgcn_mfma_f32_32x32x16_bf16(ah1, bl, acc1, 0, 0, 0);
        acc1 = __builtin_amdgcn_mfma_f32_32x32x16_bf16(al1, bh, acc1, 0, 0, 0);
    }

    // ---- bias (loaded after MFMA: 8 float4 loads, keeps MFMA reg pressure low) ----
    // lane's m-slots: m = tt*32 + 8*rq + 4*h2 + p ; r = 4*rq + p
    float4 bv4[2][4];
    #pragma unroll
    for (int tt = 0; tt < 2; ++tt)
        #pragma unroll
        for (int rq = 0; rq < 4; ++rq)
            bv4[tt][rq] = *reinterpret_cast<const float4*>(
                bias + (size_t)g * 64 + tt * 32 + 8 * rq + 4 * h2);

    // ---- epilogue: softmax over m (in-register) + dot with x ----
    float y[2][16];
    #pragma unroll
    for (int tt = 0; tt < 2; ++tt)
        #pragma unroll
        for (int rq = 0; rq < 4; ++rq) {
            const f32x16& a = tt ? acc1 : acc0;
            y[tt][4*rq+0] = a[4*rq+0] + bv4[tt][rq].x;
            y[tt][4*rq+1] = a[4*rq+1] + bv4[tt][rq].y;
            y[tt][4*rq+2] = a[4*rq+2] + bv4[tt][rq].z;
            y[tt][4*rq+3] = a[4*rq+3] + bv4[tt][rq].w;
        }

    float mx = y[0][0];
    #pragma unroll
    for (int r = 1; r < 16; ++r) mx = fmaxf(mx, y[0][r]);
    #pragma unroll
    for (int r = 0; r < 16; ++r) mx = fmaxf(mx, y[1][r]);
    mx = fmaxf(mx, __shfl_xor(mx, 32));

    float S = 0.f, P = 0.f;
    #pragma unroll
    for (int tt = 0; tt < 2; ++tt)
        #pragma unroll
        for (int j = 0; j < 4; ++j) {
            // x[c][m] for m-group tt*32 + 8j + 4*h2 .. +3  (4 consecutive m)
            const int so = c * 64 + SWZ(c, tt * 32 + 8 * j + 4 * h2);
            const short4 vh = *reinterpret_cast<const short4*>(&Xh[so]);
            const short4 vl = *reinterpret_cast<const short4*>(&Xl[so]);
            const float xv0 = bf2f(vh.x) + bf2f(vl.x);
            const float xv1 = bf2f(vh.y) + bf2f(vl.y);
            const float xv2 = bf2f(vh.z) + bf2f(vl.z);
            const float xv3 = bf2f(vh.w) + bf2f(vl.w);
            const float e0 = __expf(y[tt][4*j+0] - mx);
            const float e1 = __expf(y[tt][4*j+1] - mx);
            const float e2 = __expf(y[tt][4*j+2] - mx);
            const float e3 = __expf(y[tt][4*j+3] - mx);
            S += (e0 + e1) + (e2 + e3);
            P = __builtin_fmaf(e0, xv0, P);
            P = __builtin_fmaf(e1, xv1, P);
            P = __builtin_fmaf(e2, xv2, P);
            P = __builtin_fmaf(e3, xv3, P);
        }
    S += __shfl_xor(S, 32);
    P += __shfl_xor(P, 32);

    if (h2 == 0)
        out[(size_t)(row0 + c) * N_GROUPS + g] = P / S;
}

extern "C" void kernel_launch(void* const* d_in, const int* in_sizes, int n_in,
                              void* d_out, int out_size, void* d_ws, size_t ws_size,
                              hipStream_t stream) {
    const float* x  = (const float*)d_in[0];
    const float* W  = (const float*)d_in[1];
    const float* b  = (const float*)d_in[2];
    float* out = (float*)d_out;

    dim3 grid(BATCH / ROWS, N_GROUPS);
    dim3 block(512);
    ensemble_mfma_t<<<grid, block, 0, stream>>>(x, W, b, out);
}